// Round 3
// baseline (327.274 us; speedup 1.0000x reference)
//
#include <hip/hip_runtime.h>

// HollywoodFFT: B=4096 rows of N=4096 complex FFT (split re/im fp32).
// Radix-16 x 3 passes, 256 thr/row.
// R3: persistent blocks (grid=1024, 4 rows/block) + register prefetch of the
// next row issued right after the stage-in barrier -> HBM load latency for
// rows 1..3 hidden under a full row of compute. Hoisted row-invariant
// __sincosf. Direct coalesced stores (no stage-out LDS round).
// n = a + 16b + 256c ; k = u + 16v + 256w (digits in [0,16)):
//   S1[a][b][u] = DFT16_c x[a+16b+256c]
//   S2 = S1 * W256^{b u}
//   S3[a][u][v] = DFT16_b S2
//   S4 = S3 * W4096^{a(u+16v)}
//   X[u+16v+256w] = DFT16_a S4
// LDS layouts (word addr in [0,4096), all accesses <=2-way bank-aliased):
//   L0 (stage-in):  n (natural)
//   L1: addr(a,b,u) = a + 16*(b^u) + 256*u
//   L2: addr(a,u,v) = (a^u) + 16*(u^v) + 256*v

#define NFFT 4096

typedef float fvec4 __attribute__((ext_vector_type(4)));

__device__ __forceinline__ void fft16(float xr[16], float xi[16]) {
    // natural-order in/out 16-point DFT: bit-rev permute + 4 radix-2 DIT stages
    const int br[16] = {0,8,4,12,2,10,6,14,1,9,5,13,3,11,7,15};
    float yr[16], yi[16];
#pragma unroll
    for (int j = 0; j < 16; ++j) { yr[j] = xr[br[j]]; yi[j] = xi[br[j]]; }
    const float W16r[8] = { 1.0f,  0.92387953251128675613f,  0.70710678118654752440f,
                            0.38268343236508977173f,  0.0f, -0.38268343236508977173f,
                           -0.70710678118654752440f, -0.92387953251128675613f };
    const float W16i[8] = { 0.0f, -0.38268343236508977173f, -0.70710678118654752440f,
                           -0.92387953251128675613f, -1.0f, -0.92387953251128675613f,
                           -0.70710678118654752440f, -0.38268343236508977173f };
#pragma unroll
    for (int s = 0; s < 4; ++s) {
        const int stride = 1 << s;
        const int tm = 8 >> s;
#pragma unroll
        for (int g = 0; g < 16; g += 2 * stride) {
#pragma unroll
            for (int p = 0; p < stride; ++p) {
                const int i0 = g + p, i1 = i0 + stride;
                const float twr = W16r[p * tm], twi = W16i[p * tm];
                const float brr = yr[i1] * twr - yi[i1] * twi;
                const float bii = yr[i1] * twi + yi[i1] * twr;
                const float ar = yr[i0], ai = yi[i0];
                yr[i0] = ar + brr; yi[i0] = ai + bii;
                yr[i1] = ar - brr; yi[i1] = ai - bii;
            }
        }
    }
#pragma unroll
    for (int j = 0; j < 16; ++j) { xr[j] = yr[j]; xi[j] = yi[j]; }
}

__global__ __launch_bounds__(256, 4)
void HollywoodFFT_53584011985637_kernel(const float* __restrict__ xre,
                                        const float* __restrict__ xim,
                                        float* __restrict__ outre,
                                        float* __restrict__ outim,
                                        int rows_pb) {
    __shared__ __align__(16) float lr[NFFT];
    __shared__ __align__(16) float li[NFFT];

    const int t = threadIdx.x;
    const int a = t & 15;
    const int u = t >> 4;

    // Row-invariant twiddle bases (hoisted): pass B uses W256^u, pass C uses
    // W4096^(u2+16v2) = W4096^t.
    float sB, cB, sC, cC;
    __sincosf(-6.28318530717958647692f * (float)u * (1.0f / 256.0f), &sB, &cB);
    __sincosf(-6.28318530717958647692f * (float)t * (1.0f / 4096.0f), &sC, &cC);

    const long long row0 = (long long)blockIdx.x * rows_pb;

    // Prologue: prefetch row0 into registers (8 x float4 = 32 VGPRs)
    fvec4 pr[4], pim[4];
    {
        const fvec4* __restrict__ xr4 = (const fvec4*)(xre + row0 * NFFT);
        const fvec4* __restrict__ xi4 = (const fvec4*)(xim + row0 * NFFT);
#pragma unroll
        for (int q = 0; q < 4; ++q) { pr[q] = xr4[t + 256 * q]; pim[q] = xi4[t + 256 * q]; }
    }

    for (int i = 0; i < rows_pb; ++i) {
        const long long row = row0 + i;

        // ---- Stage-in: prefetched registers -> LDS natural layout ----
#pragma unroll
        for (int q = 0; q < 4; ++q) {
            ((fvec4*)lr)[t + 256 * q] = pr[q];
            ((fvec4*)li)[t + 256 * q] = pim[q];
        }
        __syncthreads();

        // ---- Issue next row's global loads NOW (used next iteration ->
        //      latency hidden under passes A/B/C of this row) ----
        if (i + 1 < rows_pb) {
            const fvec4* __restrict__ xr4 = (const fvec4*)(xre + (row + 1) * NFFT);
            const fvec4* __restrict__ xi4 = (const fvec4*)(xim + (row + 1) * NFFT);
#pragma unroll
            for (int q = 0; q < 4; ++q) { pr[q] = xr4[t + 256 * q]; pim[q] = xi4[t + 256 * q]; }
        }

        float vr[16], vi[16];

        // ---- Pass A: thread (a, b=t>>4), DFT16 over c. read n = t + 256c ----
#pragma unroll
        for (int c = 0; c < 16; ++c) { vr[c] = lr[t + 256 * c]; vi[c] = li[t + 256 * c]; }
        fft16(vr, vi);
        __syncthreads();                 // all L0 reads done before L1 writes
#pragma unroll
        for (int uu = 0; uu < 16; ++uu) {     // L1: a + 16*(b^u) + 256*u ; b = t>>4
            const int id = a + 16 * ((t >> 4) ^ uu) + 256 * uu;
            lr[id] = vr[uu]; li[id] = vi[uu];
        }
        __syncthreads();

        // ---- Pass B: thread (a, u). Read over b w/ twiddle W256^{bu}, DFT16 over b ----
        {
            float twr = 1.0f, twi = 0.0f;
#pragma unroll
            for (int bb = 0; bb < 16; ++bb) {
                const int id = a + 16 * (bb ^ u) + 256 * u;
                const float rr = lr[id], ii = li[id];
                vr[bb] = rr * twr - ii * twi;
                vi[bb] = rr * twi + ii * twr;
                const float ntr = twr * cB - twi * sB;
                twi = twr * sB + twi * cB;
                twr = ntr;
            }
        }
        fft16(vr, vi);
        __syncthreads();                 // all L1 reads done before L2 writes
#pragma unroll
        for (int v = 0; v < 16; ++v) {   // L2: (a^u) + 16*(u^v) + 256*v
            const int id = (a ^ u) + 16 * (u ^ v) + 256 * v;
            lr[id] = vr[v]; li[id] = vi[v];
        }
        __syncthreads();

        // ---- Pass C: thread (u2=a, v2=u). Read over a w/ twiddle W4096^{aa*t},
        //      DFT16 over aa, store X[t + 256w] coalesced ----
        {
            float twr = 1.0f, twi = 0.0f;
#pragma unroll
            for (int aa = 0; aa < 16; ++aa) {
                const int id = (aa ^ a) + 16 * (a ^ u) + 256 * u;
                const float rr = lr[id], ii = li[id];
                vr[aa] = rr * twr - ii * twi;
                vi[aa] = rr * twi + ii * twr;
                const float ntr = twr * cC - twi * sC;
                twi = twr * sC + twi * cC;
                twr = ntr;
            }
        }
        fft16(vr, vi);

        {
            float* __restrict__ or_row = outre + row * NFFT;
            float* __restrict__ oi_row = outim + row * NFFT;
#pragma unroll
            for (int w = 0; w < 16; ++w) {
                __builtin_nontemporal_store(vr[w], or_row + t + 256 * w);
                __builtin_nontemporal_store(vi[w], oi_row + t + 256 * w);
            }
        }
        __syncthreads();                 // L2 reads done before next row's stage-in
    }
}

extern "C" void kernel_launch(void* const* d_in, const int* in_sizes, int n_in,
                              void* d_out, int out_size, void* d_ws, size_t ws_size,
                              hipStream_t stream) {
    const float* xre = (const float*)d_in[0];
    const float* xim = (const float*)d_in[1];
    const int B = in_sizes[0] / NFFT;            // 4096 rows
    float* out = (float*)d_out;
    float* outre = out;
    float* outim = out + (size_t)B * NFFT;       // outputs concatenated flat

    int grid = 1024;
    if (grid > B) grid = B;
    const int rows_pb = B / grid;                // 4 rows per block
    HollywoodFFT_53584011985637_kernel<<<dim3(grid), dim3(256), 0, stream>>>(
        xre, xim, outre, outim, rows_pb);
}